// Round 5
// baseline (154.054 us; speedup 1.0000x reference)
//
#include <hip/hip_runtime.h>

#define NEGV -10000.0f

typedef _Float16 f16x8 __attribute__((ext_vector_type(8)));
typedef _Float16 f16x2 __attribute__((ext_vector_type(2)));
typedef float floatx4 __attribute__((ext_vector_type(4)));

// key (0..319) -> source sequence row. keys 0..63 local to query block nblk,
// keys 64..319 are the 256 global positions {0,61,62,63}+64j.
__device__ __forceinline__ int src_row(int key, int nblk) {
    if (key < 64) return nblk * 64 + key;
    int g = key - 64;
    int p = g & 3;
    return (g >> 2) * 64 + (p ? (60 + p) : 0);
}

__device__ __forceinline__ f16x8 cvt8(const float4& f0, const float4& f1) {
    f16x8 o;
    o[0] = (_Float16)f0.x; o[1] = (_Float16)f0.y;
    o[2] = (_Float16)f0.z; o[3] = (_Float16)f0.w;
    o[4] = (_Float16)f1.x; o[5] = (_Float16)f1.y;
    o[6] = (_Float16)f1.z; o[7] = (_Float16)f1.w;
    return o;
}

// Swapped-QK + key permutation L(t,n) = 32*(t>>1) + 8*(n>>2) + 4*(t&1) + (n&3):
//   acc[t][r] at lane (quad,m) = S[L(t,4*quad+r)][qrow m]; pf[kc][4h+r] =
//   acc[2kc+h][r] is the PV A-fragment (pure in-lane cvt, no P round-trip).
// Round 5: 2-chunk key split (160+160) with exact two-pass softmax stitching.
// acc halves to 10 tiles (40 regs); design peak ~115 unified regs ->
// __launch_bounds__(256,4): 4 waves/SIMD, 4 blocks/CU (4 x 40KB LDS = 160KB).
// K staging = round-1's reg-staged f16 path (empirically best of 4 variants).
// LDS: region A = chunk-0 K image (20KB), region B = chunk-1 K image (20KB);
// VT_c (f16, XOR (t<<4) swizzle) overlays region c after QK_c reads finish.
__global__ __launch_bounds__(256, 4)
void sparse_attn_kernel(const float* __restrict__ Q, const float* __restrict__ K,
                        const float* __restrict__ V, const float* __restrict__ M,
                        float* __restrict__ O)
{
    // XCD swizzle: 4 whole heads per XCD so the head's K/V rows stay in L2.
    const int x    = blockIdx.x;
    const int bh   = (x & 7) * 4 + ((x >> 3) >> 6);   // 0..31
    const int nblk = (x >> 3) & 63;                   // query block in head
    const int b    = bh >> 4;

    const size_t hoff = (size_t)bh * (4096 * 64);
    const float* Qh = Q + hoff;
    const float* Kh = K + hoff;
    const float* Vh = V + hoff;
    float*       Oh = O + hoff;
    const float* Mb = M + (size_t)b * 4096;

    __shared__ _Float16 smem[20480];   // 40KB: [0,10240) region A, [10240,20480) B

    const int tid  = threadIdx.x;
    const int lane = tid & 63;
    const int wv   = tid >> 6;          // wave -> query rows wv*16..+15
    const int m    = lane & 15;
    const int quad = lane >> 4;
    const int cg   = tid & 15;          // V col granule (4 floats)
    const int pg   = tid >> 4;          // V key-pair sub-index (0..15)

    // ---- mask: 5 values per lane + all-ones fast-path ballot ----
    float mv2[5];
    unsigned long long bb = 0ull;
    #pragma unroll
    for (int s = 0; s < 5; ++s) {
        float mval = Mb[src_row(s * 64 + lane, nblk)];
        bb |= __ballot(mval == 0.0f);
        mv2[s] = (mval == 0.0f) ? NEGV : 0.0f;
    }

    // ---- Q fragments direct from global (fp16); B-operand of swapped QK ----
    const int qrow = nblk * 64 + wv * 16 + m;
    f16x8 qf[2];
    #pragma unroll
    for (int c = 0; c < 2; ++c) {
        const float* src = Qh + (size_t)qrow * 64 + c * 32 + quad * 8;
        float4 f0 = *(const float4*)src;
        float4 f1 = *(const float4*)(src + 4);
        qf[c] = cvt8(f0, f1);
    }

    // ---- stage K (both chunks, 40KB) in A-fragment layout, key-permuted ----
    #pragma unroll
    for (int it = 0; it < 10; ++it) {
        int S    = it * 256 + tid;                       // 16B slot id, 0..2559
        int t    = S >> 7;
        int n    = S & 15;
        int col0 = ((S >> 6) & 1) * 32 + ((S & 63) >> 4) * 8;
        int lkey = 32 * (t >> 1) + 8 * (n >> 2) + 4 * (t & 1) + (n & 3);
        const float* src = Kh + (size_t)src_row(lkey, nblk) * 64 + col0;
        float4 f0 = *(const float4*)src;
        float4 f1 = *(const float4*)(src + 4);
        *(f16x8*)(&smem[S * 8]) = cvt8(f0, f1);
    }

    // ---- V helpers: granule it = keys 32it..32it+31; chunk from it ----
    auto v_load = [&](int it, float4& f0, float4& f1) {
        int l0 = 2 * (it * 16 + pg);
        f0 = *(const float4*)(Vh + (size_t)src_row(l0,     nblk) * 64 + cg * 4);
        f1 = *(const float4*)(Vh + (size_t)src_row(l0 + 1, nblk) * 64 + cg * 4);
    };
    auto vt_store = [&](int it, const float4& f0, const float4& f1) {
        int itl   = (it < 5) ? it : it - 5;
        int off   = (it < 5) ? 0 : 10240;
        int td    = cg >> 2;
        int sw    = td << 4;
        int lbase = off + (itl * 4 + td) * 512 + (pg >> 2) * 128
                  + (cg & 3) * 32 + 2 * (pg & 3);
        f16x2 pk0; pk0[0] = (_Float16)f0.x; pk0[1] = (_Float16)f1.x;
        *(f16x2*)(&smem[(lbase +  0) ^ sw]) = pk0;
        f16x2 pk1; pk1[0] = (_Float16)f0.y; pk1[1] = (_Float16)f1.y;
        *(f16x2*)(&smem[(lbase +  8) ^ sw]) = pk1;
        f16x2 pk2; pk2[0] = (_Float16)f0.z; pk2[1] = (_Float16)f1.z;
        *(f16x2*)(&smem[(lbase + 16) ^ sw]) = pk2;
        f16x2 pk3; pk3[0] = (_Float16)f0.w; pk3[1] = (_Float16)f1.w;
        *(f16x2*)(&smem[(lbase + 24) ^ sw]) = pk3;
    };

    floatx4 acc[10];
    // mask add for tiles tg0..tg0+9 into acc (global-tile lb formula, round 1)
    auto mask_add = [&](int tg0) {
        if (bb != 0ull) {
            #pragma unroll
            for (int tl = 0; tl < 10; ++tl) {
                int tg = tg0 + tl;
                int lb = 32 * ((tg >> 1) & 1) + 4 * (tg & 1) + 8 * quad;
                #pragma unroll
                for (int r = 0; r < 4; ++r)
                    acc[tl][r] += __shfl(mv2[tg >> 2], lb + r, 64);
            }
        }
    };

    // ---- V chunk-0 flight: granules 0..2 (24 regs); land during QK_0 ----
    float4 a0, b0, a1, b1, a2, b2;
    v_load(0, a0, b0);
    v_load(1, a1, b1);
    v_load(2, a2, b2);

    __syncthreads();   // B1: K image (both chunks) complete

    // ---- QK_0: tiles 0..9 (keys 0..159), region A ----
    #pragma unroll
    for (int t = 0; t < 10; ++t) {
        acc[t] = floatx4{0.f, 0.f, 0.f, 0.f};
        #pragma unroll
        for (int c = 0; c < 2; ++c) {
            f16x8 kf = *(const f16x8*)(&smem[(t * 2 + c) * 512 + lane * 8]);
            acc[t] = __builtin_amdgcn_mfma_f32_16x16x32_f16(kf, qf[c], acc[t], 0, 0, 0);
        }
    }

    __syncthreads();   // B2: region A QK reads done -> VT_0 may overlay

    vt_store(0, a0, b0);
    vt_store(1, a1, b1);
    vt_store(2, a2, b2);
    v_load(3, a0, b0);
    v_load(4, a1, b1);

    mask_add(0);

    // ---- chunk-0 stats: m0, e = exp(s-m0), s0 (lane owns q-row m) ----
    float m0 = -3e38f;
    #pragma unroll
    for (int tl = 0; tl < 10; ++tl)
        #pragma unroll
        for (int r = 0; r < 4; ++r)
            m0 = fmaxf(m0, acc[tl][r]);
    m0 = fmaxf(m0, __shfl_xor(m0, 16, 64));
    m0 = fmaxf(m0, __shfl_xor(m0, 32, 64));
    float s0 = 0.f;
    #pragma unroll
    for (int tl = 0; tl < 10; ++tl)
        #pragma unroll
        for (int r = 0; r < 4; ++r) {
            float e = __expf(acc[tl][r] - m0);
            acc[tl][r] = e;
            s0 += e;
        }
    s0 += __shfl_xor(s0, 16, 64);
    s0 += __shfl_xor(s0, 32, 64);

    vt_store(3, a0, b0);
    vt_store(4, a1, b1);

    // ---- pf0: in-lane cvt (unnormalized, e <= 1); acc freed for chunk 1 ----
    f16x8 pf0[5];
    #pragma unroll
    for (int kc = 0; kc < 5; ++kc)
        #pragma unroll
        for (int r = 0; r < 4; ++r) {
            pf0[kc][r]     = (_Float16)acc[2 * kc][r];
            pf0[kc][4 + r] = (_Float16)acc[2 * kc + 1][r];
        }

    __syncthreads();   // B3: VT_0 image complete

    // ---- V chunk-1 flight: granules 5..7; land during PV_0 + QK_1 ----
    v_load(5, a0, b0);
    v_load(6, a1, b1);
    v_load(7, a2, b2);

    // ---- PV_0: 20 MFMA from region A ----
    floatx4 oacc[4] = {};
    #pragma unroll
    for (int kc = 0; kc < 5; ++kc) {
        #pragma unroll
        for (int t = 0; t < 4; ++t) {
            f16x8 vf = *(const f16x8*)(&smem[(kc * 4 + t) * 512 + ((lane * 8) ^ (t << 4))]);
            oacc[t] = __builtin_amdgcn_mfma_f32_16x16x32_f16(pf0[kc], vf, oacc[t], 0, 0, 0);
        }
    }

    // ---- QK_1: tiles 10..19 (keys 160..319), region B ----
    #pragma unroll
    for (int t = 0; t < 10; ++t) {
        acc[t] = floatx4{0.f, 0.f, 0.f, 0.f};
        #pragma unroll
        for (int c = 0; c < 2; ++c) {
            f16x8 kf = *(const f16x8*)(&smem[((10 + t) * 2 + c) * 512 + lane * 8]);
            acc[t] = __builtin_amdgcn_mfma_f32_16x16x32_f16(kf, qf[c], acc[t], 0, 0, 0);
        }
    }

    __syncthreads();   // B4: region B QK reads done -> VT_1 may overlay

    vt_store(5, a0, b0);
    vt_store(6, a1, b1);
    vt_store(7, a2, b2);
    v_load(8, a0, b0);
    v_load(9, a1, b1);

    mask_add(10);

    // ---- chunk-1 stats vs global max; exact stitch ----
    float m1 = -3e38f;
    #pragma unroll
    for (int tl = 0; tl < 10; ++tl)
        #pragma unroll
        for (int r = 0; r < 4; ++r)
            m1 = fmaxf(m1, acc[tl][r]);
    m1 = fmaxf(m1, __shfl_xor(m1, 16, 64));
    m1 = fmaxf(m1, __shfl_xor(m1, 32, 64));
    const float mg = fmaxf(m0, m1);
    float s1 = 0.f;
    #pragma unroll
    for (int tl = 0; tl < 10; ++tl)
        #pragma unroll
        for (int r = 0; r < 4; ++r) {
            float e = __expf(acc[tl][r] - mg);
            acc[tl][r] = e;
            s1 += e;
        }
    s1 += __shfl_xor(s1, 16, 64);
    s1 += __shfl_xor(s1, 32, 64);
    const float f0   = __expf(m0 - mg);          // chunk-0 rescale, <= 1
    const float zinv = 1.0f / (f0 * s0 + s1);    // global 1/rowsum

    // ---- rescale oacc by per-row f0 (exact two-pass stitch) ----
    float f0r[4];
    #pragma unroll
    for (int r = 0; r < 4; ++r)
        f0r[r] = __shfl(f0, quad * 4 + r, 64);
    #pragma unroll
    for (int t = 0; t < 4; ++t)
        #pragma unroll
        for (int r = 0; r < 4; ++r)
            oacc[t][r] *= f0r[r];

    vt_store(8, a0, b0);
    vt_store(9, a1, b1);

    // ---- pf1: in-lane cvt (e vs global max, <= 1) ----
    f16x8 pf1[5];
    #pragma unroll
    for (int kc = 0; kc < 5; ++kc)
        #pragma unroll
        for (int r = 0; r < 4; ++r) {
            pf1[kc][r]     = (_Float16)acc[2 * kc][r];
            pf1[kc][4 + r] = (_Float16)acc[2 * kc + 1][r];
        }

    __syncthreads();   // B5: VT_1 image complete

    // ---- PV_1: 20 MFMA from region B ----
    #pragma unroll
    for (int kc = 0; kc < 5; ++kc) {
        #pragma unroll
        for (int t = 0; t < 4; ++t) {
            f16x8 vf = *(const f16x8*)(&smem[10240 + (kc * 4 + t) * 512 + ((lane * 8) ^ (t << 4))]);
            oacc[t] = __builtin_amdgcn_mfma_f32_16x16x32_f16(pf1[kc], vf, oacc[t], 0, 0, 0);
        }
    }

    // ---- epilogue: apply global 1/rowsum per row, store fp32 ----
    float zr[4];
    #pragma unroll
    for (int r = 0; r < 4; ++r)
        zr[r] = __shfl(zinv, quad * 4 + r, 64);
    #pragma unroll
    for (int t = 0; t < 4; ++t)
        #pragma unroll
        for (int r = 0; r < 4; ++r)
            Oh[(size_t)(nblk * 64 + wv * 16 + quad * 4 + r) * 64 + t * 16 + m] =
                oacc[t][r] * zr[r];
}

extern "C" void kernel_launch(void* const* d_in, const int* in_sizes, int n_in,
                              void* d_out, int out_size, void* d_ws, size_t ws_size,
                              hipStream_t stream) {
    const float* q    = (const float*)d_in[0];
    const float* k    = (const float*)d_in[1];
    const float* v    = (const float*)d_in[2];
    const float* mask = (const float*)d_in[3];
    float* out = (float*)d_out;
    (void)in_sizes; (void)n_in; (void)out_size; (void)d_ws; (void)ws_size;
    sparse_attn_kernel<<<2 * 16 * 64, 256, 0, stream>>>(q, k, v, mask, out);
}

// Round 6
// 145.344 us; speedup vs baseline: 1.0599x; 1.0599x over previous
//
#include <hip/hip_runtime.h>

#define NEGV -10000.0f

typedef _Float16 f16x8 __attribute__((ext_vector_type(8)));
typedef _Float16 f16x2 __attribute__((ext_vector_type(2)));
typedef float floatx4 __attribute__((ext_vector_type(4)));

// key (0..319) -> source sequence row. keys 0..63 local to query block nblk,
// keys 64..319 are the 256 global positions {0,61,62,63}+64j.
__device__ __forceinline__ int src_row(int key, int nblk) {
    if (key < 64) return nblk * 64 + key;
    int g = key - 64;
    int p = g & 3;
    return (g >> 2) * 64 + (p ? (60 + p) : 0);
}

__device__ __forceinline__ f16x8 cvt8(const float4& f0, const float4& f1) {
    f16x8 o;
    o[0] = (_Float16)f0.x; o[1] = (_Float16)f0.y;
    o[2] = (_Float16)f0.z; o[3] = (_Float16)f0.w;
    o[4] = (_Float16)f1.x; o[5] = (_Float16)f1.y;
    o[6] = (_Float16)f1.z; o[7] = (_Float16)f1.w;
    return o;
}

// Swapped-QK + key permutation L(t,n) = 32*(t>>1) + 8*(n>>2) + 4*(t&1) + (n&3):
//   acc[t][r] at lane (quad,m) = S[L(t,4*quad+r)][qrow m]; P fragment for PV is
//   a pure in-lane cvt of acc (no LDS round-trip). Tiles 0..3 = local keys
//   0..63; tiles 4..19 = global keys 64..319 (identical for all qblocks).
// Round 6: persistent slice blocks. 512 blocks (2/CU, all co-resident), each
// owns 4 consecutive qblocks of one head. Global K image (32KB) + global VT
// image (32KB) staged ONCE; per-iter only local K (8KB) + local VT (8KB) are
// staged, with next-iter K/V/Q/mask prefetched to registers under the current
// iter's MFMA+softmax. 2 barriers/iter. launch_bounds(256,2): 256-reg budget,
// prefetch stays in flight, no spills (WRITE_SIZE tripwire).
__global__ __launch_bounds__(256, 2)
void sparse_attn_kernel(const float* __restrict__ Q, const float* __restrict__ K,
                        const float* __restrict__ V, const float* __restrict__ M,
                        float* __restrict__ O)
{
    const int x     = blockIdx.x;                     // 512 blocks
    const int bh    = (x & 7) * 4 + ((x >> 3) >> 4);  // 4 whole heads per XCD
    const int slice = (x >> 3) & 15;                  // 16 slices per head
    const int b     = bh >> 4;
    const int nblk0 = slice * 4;

    const size_t hoff = (size_t)bh * (4096 * 64);
    const float* Qh = Q + hoff;
    const float* Kh = K + hoff;
    const float* Vh = V + hoff;
    float*       Oh = O + hoff;
    const float* Mb = M + (size_t)b * 4096;

    // 80KB: [0,16384) global K (32 slabs x 512 f16, slab (t-4)*2+c);
    // [16384,32768) global VT (32 slabs, slab k2g*4+t, XOR (t<<4) swizzle);
    // [32768,36864) local K (8 slabs, slab t*2+c);
    // [36864,40960) local VT (8 slabs, slab k2l*4+t).
    __shared__ _Float16 smem[40960];
    constexpr int GVT = 16384, LKo = 32768, LVT = 36864;   // global K at 0

    const int tid  = threadIdx.x;
    const int lane = tid & 63;
    const int wv   = tid >> 6;          // wave -> query rows wv*16..+15
    const int m    = lane & 15;
    const int quad = lane >> 4;
    const int cg   = tid & 15;          // V col granule (4 floats)
    const int pg   = tid >> 4;          // V key-pair sub-index (0..15)

    // ---- helpers ----
    auto vt_store_at = [&](int base, int k2, const float4& f0, const float4& f1) {
        int td    = cg >> 2;
        int sw    = td << 4;
        int lbase = base + (k2 * 4 + td) * 512 + (pg >> 2) * 128
                  + (cg & 3) * 32 + 2 * (pg & 3);
        f16x2 pk0; pk0[0] = (_Float16)f0.x; pk0[1] = (_Float16)f1.x;
        *(f16x2*)(&smem[(lbase +  0) ^ sw]) = pk0;
        f16x2 pk1; pk1[0] = (_Float16)f0.y; pk1[1] = (_Float16)f1.y;
        *(f16x2*)(&smem[(lbase +  8) ^ sw]) = pk1;
        f16x2 pk2; pk2[0] = (_Float16)f0.z; pk2[1] = (_Float16)f1.z;
        *(f16x2*)(&smem[(lbase + 16) ^ sw]) = pk2;
        f16x2 pk3; pk3[0] = (_Float16)f0.w; pk3[1] = (_Float16)f1.w;
        *(f16x2*)(&smem[(lbase + 24) ^ sw]) = pk3;
    };
    auto q_load = [&](int nblk, float4* qn) {
        const float* src = Qh + (size_t)(nblk * 64 + wv * 16 + m) * 64 + quad * 8;
        qn[0] = *(const float4*)src;        qn[1] = *(const float4*)(src + 4);
        qn[2] = *(const float4*)(src + 32); qn[3] = *(const float4*)(src + 36);
    };
    auto lk_load = [&](int nblk, float4* kn) {     // local K tiles 0..3, 2 slots
        #pragma unroll
        for (int s2 = 0; s2 < 2; ++s2) {
            int S    = s2 * 256 + tid;              // 0..511
            int t    = S >> 7;
            int n    = S & 15;
            int col0 = ((S >> 6) & 1) * 32 + ((S & 63) >> 4) * 8;
            int lkey = 32 * (t >> 1) + 8 * (n >> 2) + 4 * (t & 1) + (n & 3);
            const float* src = Kh + (size_t)(nblk * 64 + lkey) * 64 + col0;
            kn[2 * s2]     = *(const float4*)src;
            kn[2 * s2 + 1] = *(const float4*)(src + 4);
        }
    };
    auto lk_write = [&](const float4* kn) {
        #pragma unroll
        for (int s2 = 0; s2 < 2; ++s2) {
            int S = s2 * 256 + tid;
            *(f16x8*)(&smem[LKo + S * 8]) = cvt8(kn[2 * s2], kn[2 * s2 + 1]);
        }
    };
    auto lv_load = [&](int nblk, float4* vn) {     // local V keys 0..63
        #pragma unroll
        for (int g = 0; g < 2; ++g) {
            int l0 = 2 * (g * 16 + pg);             // 0..63
            vn[2 * g]     = *(const float4*)(Vh + (size_t)(nblk * 64 + l0) * 64 + cg * 4);
            vn[2 * g + 1] = *(const float4*)(Vh + (size_t)(nblk * 64 + l0 + 1) * 64 + cg * 4);
        }
    };
    auto lv_write = [&](const float4* vn) {
        vt_store_at(LVT, 0, vn[0], vn[1]);
        vt_store_at(LVT, 1, vn[2], vn[3]);
    };

    // ---- mask: global part fixed for the whole block ----
    float mv2[5];
    unsigned long long bbg = 0ull;
    #pragma unroll
    for (int s = 1; s < 5; ++s) {
        float mval = Mb[src_row(s * 64 + lane, 0)];
        bbg |= __ballot(mval == 0.0f);
        mv2[s] = (mval == 0.0f) ? NEGV : 0.0f;
    }

    // ---- prologue: stage global K image (tiles 4..19) ----
    #pragma unroll
    for (int it = 0; it < 8; ++it) {
        int S    = it * 256 + tid;                  // 0..2047
        int t    = (S >> 7) + 4;
        int n    = S & 15;
        int col0 = ((S >> 6) & 1) * 32 + ((S & 63) >> 4) * 8;
        int lkey = 32 * (t >> 1) + 8 * (n >> 2) + 4 * (t & 1) + (n & 3);  // >=64
        const float* src = Kh + (size_t)src_row(lkey, 0) * 64 + col0;
        float4 f0 = *(const float4*)src;
        float4 f1 = *(const float4*)(src + 4);
        *(f16x8*)(&smem[S * 8]) = cvt8(f0, f1);
    }
    // ---- prologue: stage global VT image (keys 64..319, granules 2..9) ----
    #pragma unroll
    for (int it = 2; it < 10; ++it) {
        int l0 = 2 * (it * 16 + pg);                // 64..319
        float4 f0 = *(const float4*)(Vh + (size_t)src_row(l0,     0) * 64 + cg * 4);
        float4 f1 = *(const float4*)(Vh + (size_t)src_row(l0 + 1, 0) * 64 + cg * 4);
        vt_store_at(GVT, it - 2, f0, f1);
    }
    // ---- prologue: iter-0 locals + Q + local mask ----
    float4 qn[4], kn[4], vn[4];
    q_load(nblk0, qn);
    lk_load(nblk0, kn);
    lv_load(nblk0, vn);
    lk_write(kn);
    lv_write(vn);
    float mloc = Mb[(size_t)nblk0 * 64 + lane];

    __syncthreads();   // B1: all images complete

    // ---- main loop: 4 qblocks, locals double-pumped through registers ----
    #pragma unroll
    for (int i = 0; i < 4; ++i) {
        const int nblk = nblk0 + i;
        f16x8 qf[2] = { cvt8(qn[0], qn[1]), cvt8(qn[2], qn[3]) };
        const float mloc_c = mloc;

        // QK: 40 MFMA (tiles 0..3 local region, 4..19 global region)
        floatx4 acc[20];
        #pragma unroll
        for (int t = 0; t < 20; ++t) {
            acc[t] = floatx4{0.f, 0.f, 0.f, 0.f};
            #pragma unroll
            for (int c = 0; c < 2; ++c) {
                const int slab = (t < 4) ? (LKo + (t * 2 + c) * 512)
                                         : (((t - 4) * 2 + c) * 512);
                f16x8 kf = *(const f16x8*)(&smem[slab + lane * 8]);
                acc[t] = __builtin_amdgcn_mfma_f32_16x16x32_f16(kf, qf[c], acc[t], 0, 0, 0);
            }
        }

        // prefetch next iteration's locals under softmax latency
        if (i < 3) {
            q_load(nblk + 1, qn);
            lk_load(nblk + 1, kn);
            lv_load(nblk + 1, vn);
            mloc = Mb[(size_t)(nblk + 1) * 64 + lane];
        }

        // mask slow path
        unsigned long long bb = bbg | __ballot(mloc_c == 0.0f);
        if (bb != 0ull) {
            mv2[0] = (mloc_c == 0.0f) ? NEGV : 0.0f;
            #pragma unroll
            for (int t = 0; t < 20; ++t) {
                int lb = 32 * ((t >> 1) & 1) + 4 * (t & 1) + 8 * quad;
                #pragma unroll
                for (int r = 0; r < 4; ++r)
                    acc[t][r] += __shfl(mv2[t >> 2], lb + r, 64);
            }
        }

        // softmax over 320 keys: lane owns q-row m; reduce across quads
        float rmax = -3e38f;
        #pragma unroll
        for (int t = 0; t < 20; ++t)
            #pragma unroll
            for (int r = 0; r < 4; ++r)
                rmax = fmaxf(rmax, acc[t][r]);
        rmax = fmaxf(rmax, __shfl_xor(rmax, 16, 64));
        rmax = fmaxf(rmax, __shfl_xor(rmax, 32, 64));
        float rsum = 0.f;
        #pragma unroll
        for (int t = 0; t < 20; ++t)
            #pragma unroll
            for (int r = 0; r < 4; ++r) {
                float e = __expf(acc[t][r] - rmax);
                acc[t][r] = e;
                rsum += e;
            }
        rsum += __shfl_xor(rsum, 16, 64);
        rsum += __shfl_xor(rsum, 32, 64);
        const float rinv = 1.0f / rsum;

        // PV: 40 MFMA; P built in-lane per k2 with 1/rowsum folded in
        floatx4 oacc[4] = {};
        #pragma unroll
        for (int k2 = 0; k2 < 10; ++k2) {
            f16x8 p;
            #pragma unroll
            for (int r = 0; r < 4; ++r) {
                p[r]     = (_Float16)(acc[2 * k2][r]     * rinv);
                p[4 + r] = (_Float16)(acc[2 * k2 + 1][r] * rinv);
            }
            #pragma unroll
            for (int t = 0; t < 4; ++t) {
                const int base = (k2 < 2) ? (LVT + (k2 * 4 + t) * 512)
                                          : (GVT + ((k2 - 2) * 4 + t) * 512);
                f16x8 vf = *(const f16x8*)(&smem[base + ((lane * 8) ^ (t << 4))]);
                oacc[t] = __builtin_amdgcn_mfma_f32_16x16x32_f16(p, vf, oacc[t], 0, 0, 0);
            }
        }

        // store O (P pre-normalized)
        #pragma unroll
        for (int t = 0; t < 4; ++t)
            #pragma unroll
            for (int r = 0; r < 4; ++r)
                Oh[(size_t)(nblk * 64 + wv * 16 + quad * 4 + r) * 64 + t * 16 + m] =
                    oacc[t][r];

        // rotate local images for next iteration
        if (i < 3) {
            __syncthreads();   // all QK reads of LK + PV reads of LVT done
            lk_write(kn);
            lv_write(vn);
            __syncthreads();   // new local images visible
        }
    }
}

extern "C" void kernel_launch(void* const* d_in, const int* in_sizes, int n_in,
                              void* d_out, int out_size, void* d_ws, size_t ws_size,
                              hipStream_t stream) {
    const float* q    = (const float*)d_in[0];
    const float* k    = (const float*)d_in[1];
    const float* v    = (const float*)d_in[2];
    const float* mask = (const float*)d_in[3];
    float* out = (float*)d_out;
    (void)in_sizes; (void)n_in; (void)out_size; (void)d_ws; (void)ws_size;
    sparse_attn_kernel<<<512, 256, 0, stream>>>(q, k, v, mask, out);
}